// Round 1
// baseline (217.894 us; speedup 1.0000x reference)
//
#include <hip/hip_runtime.h>

// GraphSAGEConv: out_i = mean_{j in N(i)} x_j @ W_l + b_l + x_i @ W_r
// N=100000, E=1600000, D_in=D_out=64.
//
// 5 dispatches:
//   memset:  bcnt/bfill (tiny)
//   prep:    convert x->bf16 xh, Wl/Wr->bf16  +  coarse bucket histogram
//            (256-node buckets, per-block LDS hist; 512 hist blocks)
//   bscan:   1-block scan -> bbase[]
//   binpass: group edges by coarse bucket, packed (src<<8)|(dst&255), written
//            line-dense into bucket regions of binned (512 blocks x 512 thr)
//   sage_fused: one block per 64 nodes (quarter bucket), 512 threads (8 waves):
//            - blockIdx swizzled so the 4 quarters of a bucket share an XCD
//              (binned re-reads become L2 hits)
//            - filter+fine-sort its edges into LDS
//            - per-wave aggregation: 8 nodes/wave, half-wave ushort2 gathers of
//              128B bf16 rows, 8-deep ILP, f32 accumulate
//            - means staged bf16 in LDS (72-short row pitch: conflict-free)
//            - each wave computes 2 row-tiles x 16 cols of the 64x64 out tile
//              via mfma_f32_16x16x32_bf16 (fuses both GEMMs, K=128)

#define DFEAT 64
#define MAXBUCK 512                  // coarse buckets (256 nodes), N <= 131072
#define SORT_CAP 2048                // LDS edge capacity per 64-node block
#define MLD 72                       // means row pitch in shorts (bank-safe)

typedef short bf16x8 __attribute__((ext_vector_type(8)));
typedef float f32x4 __attribute__((ext_vector_type(4)));

static __device__ __forceinline__ unsigned short f2bf(float f) {
    unsigned int u = __float_as_uint(f);
    unsigned int r = (u + 0x7FFFu + ((u >> 16) & 1u)) >> 16;   // RNE
    return (unsigned short)r;
}
static __device__ __forceinline__ float bf2f_lo(unsigned int u) {
    return __uint_as_float(u << 16);
}
static __device__ __forceinline__ float bf2f_hi(unsigned int u) {
    return __uint_as_float(u & 0xFFFF0000u);
}

// convert (blocks [0, convBlocks)) + coarse histogram (blocks [convBlocks, +512))
__launch_bounds__(256)
__global__ void prep(const float* __restrict__ x,
                     const float* __restrict__ Wl,
                     const float* __restrict__ Wr,
                     const int* __restrict__ dst,
                     unsigned short* __restrict__ xh,
                     unsigned short* __restrict__ wl16,
                     unsigned short* __restrict__ wr16,
                     int* __restrict__ bcnt,
                     int nx4, int convBlocks, int E, int nbuck) {
    __shared__ int h[MAXBUCK];
    int b = blockIdx.x, t = threadIdx.x;
    if (b < convBlocks) {
        int i = b * 256 + t;
        const float* sp; unsigned short* dp; int k;
        if (i < 1024)      { sp = Wl; dp = wl16; k = i; }
        else if (i < 2048) { sp = Wr; dp = wr16; k = i - 1024; }
        else if (i - 2048 < nx4) { sp = x; dp = xh; k = i - 2048; }
        else return;
        float4 v = ((const float4*)sp)[k];
        ushort4 hh;
        hh.x = f2bf(v.x); hh.y = f2bf(v.y); hh.z = f2bf(v.z); hh.w = f2bf(v.w);
        ((ushort4*)dp)[k] = hh;
        return;
    }
    int hb = b - convBlocks;                    // 0..511
    for (int i = t; i < nbuck; i += 256) h[i] = 0;
    __syncthreads();
    int chunk = (E + 511) / 512;
    int lo = hb * chunk;
    int hi = lo + chunk; if (hi > E) hi = E;
    for (int i = lo + t; i < hi; i += 256)
        atomicAdd(&h[((unsigned)dst[i]) >> 8], 1);
    __syncthreads();
    for (int i = t; i < nbuck; i += 256)
        if (h[i]) atomicAdd(&bcnt[i], h[i]);
}

// One-block exclusive scan of bucket counts -> bbase[0..nbuck].
__global__ void bscan(const int* __restrict__ bcnt, int* __restrict__ bbase,
                      int nbuck) {
    __shared__ int a[2][MAXBUCK];
    int t = threadIdx.x;                        // blockDim = MAXBUCK
    a[0][t] = (t < nbuck) ? bcnt[t] : 0;
    __syncthreads();
    int cur = 0;
    for (int o = 1; o < MAXBUCK; o <<= 1) {
        a[cur ^ 1][t] = a[cur][t] + ((t >= o) ? a[cur][t - o] : 0);
        cur ^= 1;
        __syncthreads();
    }
    if (t < nbuck) bbase[t] = (t == 0) ? 0 : a[cur][t - 1];
    if (t == 0) bbase[nbuck] = a[cur][nbuck - 1];
}

// Group edges by coarse bucket; write packed (src<<8 | dst&255) line-dense.
__launch_bounds__(512)
__global__ void binpass(const int* __restrict__ src, const int* __restrict__ dst,
                        const int* __restrict__ bbase, int* __restrict__ bfill,
                        unsigned int* __restrict__ binned, int E, int nbuck) {
    __shared__ int hcnt[MAXBUCK];
    __shared__ int hbase[MAXBUCK];
    int t = threadIdx.x;
    int chunk = (E + 511) / 512;
    int lo = blockIdx.x * chunk;
    int hi = lo + chunk; if (hi > E) hi = E;

    for (int i = t; i < nbuck; i += 512) hcnt[i] = 0;
    __syncthreads();
    for (int i = lo + t; i < hi; i += 512)
        atomicAdd(&hcnt[((unsigned)dst[i]) >> 8], 1);
    __syncthreads();
    for (int i = t; i < nbuck; i += 512) {
        int c = hcnt[i];
        hbase[i] = c > 0 ? (bbase[i] + atomicAdd(&bfill[i], c)) : 0;
        hcnt[i] = 0;
    }
    __syncthreads();
    for (int i = lo + t; i < hi; i += 512) {
        int d = dst[i];
        int bu = ((unsigned)d) >> 8;
        int p = hbase[bu] + atomicAdd(&hcnt[bu], 1);
        binned[p] = (((unsigned)src[i]) << 8) | ((unsigned)d & 255u);
    }
}

// Fused fine-sort + aggregate + dual-GEMM. One block per 64 nodes, 8 waves.
// blockIdx swizzle: i = x + 8*k, k = 4*m+q  ->  bucket cb = x + 8*m, quarter q.
// All 4 quarters of a bucket share x = i%8 (same XCD under round-robin
// dispatch) so the bucket's binned lines are fetched into one L2 once.
__launch_bounds__(512)
__global__ void sage_fused(const unsigned short* __restrict__ xh,
                           const unsigned int* __restrict__ binned,
                           const int* __restrict__ bbase,
                           const unsigned short* __restrict__ wl16,
                           const unsigned short* __restrict__ wr16,
                           const float* __restrict__ bl,
                           float* __restrict__ out, int N, int nbuck) {
    __shared__ int scnt[64];
    __shared__ int sbase[64];
    __shared__ int sfill[64];
    __shared__ int sortbuf[SORT_CAP];
    __shared__ unsigned short means[64 * MLD];   // 9216 B

    int xx = blockIdx.x & 7;
    int k  = blockIdx.x >> 3;
    int cb = xx + ((k >> 2) << 3);  // coarse bucket
    int q  = k & 3;                 // 64-node quarter
    if (cb >= nbuck) return;
    int n0 = (cb << 8) + (q << 6);
    if (n0 >= N) return;
    int nn = N - n0; if (nn > 64) nn = 64;

    int t = threadIdx.x;
    int w = t >> 6;                 // 0..7
    int lane = t & 63;

    // ---- fine histogram (filtered to our quarter) ----
    if (t < 64) { scnt[t] = 0; sfill[t] = 0; }
    __syncthreads();
    int elo = bbase[cb], ehi = bbase[cb + 1];
    for (int i = elo + t; i < ehi; i += 512) {
        unsigned int v = binned[i];
        int dlo = (int)(v & 255u);
        if ((dlo >> 6) == q) atomicAdd(&scnt[dlo & 63], 1);
    }
    __syncthreads();
    // ---- exclusive scan of 64 counters (wave 0, shfl) ----
    if (w == 0) {
        int c = scnt[lane];
        int v = c;
        #pragma unroll
        for (int o = 1; o < 64; o <<= 1) {
            int u = __shfl_up(v, o);
            if (lane >= o) v += u;
        }
        sbase[lane] = v - c;
    }
    __syncthreads();
    // ---- place edges into LDS ----
    for (int i = elo + t; i < ehi; i += 512) {
        unsigned int v = binned[i];
        int dlo = (int)(v & 255u);
        if ((dlo >> 6) == q) {
            int d = dlo & 63;
            int p = sbase[d] + atomicAdd(&sfill[d], 1);
            if (p < SORT_CAP) sortbuf[p] = (int)(v >> 8);
        }
    }
    __syncthreads();

    // ---- aggregation: wave w handles nodes w*8 .. w*8+7 ----
    int half = lane >> 5;
    int l2 = lane & 31;
    for (int m = 0; m < 8; ++m) {
        int d = w * 8 + m;
        if (d >= nn) break;
        int s0 = sbase[d];
        int deg = scnt[d];
        int s1 = s0 + deg; if (s1 > SORT_CAP) s1 = SORT_CAP;

        float2 acc[8];
        #pragma unroll
        for (int u = 0; u < 8; ++u) { acc[u].x = 0.f; acc[u].y = 0.f; }

        for (int base = s0; base < s1; base += 64) {
            int cc = s1 - base; if (cc > 64) cc = 64;
            int myidx = (lane < cc) ? sortbuf[base + lane] : 0;
            int pairs = cc >> 1;
            int s = 0;
            for (; s + 8 <= pairs; s += 8) {
                unsigned int vv[8];
                #pragma unroll
                for (int u = 0; u < 8; ++u) {
                    int id = __shfl(myidx, 2 * (s + u) + half);
                    vv[u] = *(const unsigned int*)(xh + (size_t)id * DFEAT + l2 * 2);
                }
                #pragma unroll
                for (int u = 0; u < 8; ++u) {
                    acc[u].x += bf2f_lo(vv[u]);
                    acc[u].y += bf2f_hi(vv[u]);
                }
            }
            for (; s < pairs; ++s) {
                int id = __shfl(myidx, 2 * s + half);
                unsigned int v = *(const unsigned int*)(xh + (size_t)id * DFEAT + l2 * 2);
                acc[0].x += bf2f_lo(v);
                acc[0].y += bf2f_hi(v);
            }
            if (cc & 1) {
                int id = __shfl(myidx, cc - 1);
                unsigned int v = *(const unsigned int*)(xh + (size_t)id * DFEAT + l2 * 2);
                if (half == 0) {
                    acc[1].x += bf2f_lo(v);
                    acc[1].y += bf2f_hi(v);
                }
            }
        }

        float2 s2;
        s2.x = ((acc[0].x + acc[1].x) + (acc[2].x + acc[3].x))
             + ((acc[4].x + acc[5].x) + (acc[6].x + acc[7].x));
        s2.y = ((acc[0].y + acc[1].y) + (acc[2].y + acc[3].y))
             + ((acc[4].y + acc[5].y) + (acc[6].y + acc[7].y));
        s2.x += __shfl_xor(s2.x, 32);
        s2.y += __shfl_xor(s2.y, 32);

        if (lane < 32) {
            float inv = 1.0f / fmaxf((float)deg, 1.0f);
            unsigned int pk = (unsigned int)f2bf(s2.x * inv)
                            | ((unsigned int)f2bf(s2.y * inv) << 16);
            *(unsigned int*)&means[d * MLD + l2 * 2] = pk;
        }
    }
    __syncthreads();

    // ---- GEMM: wave w -> col quadrant (w&3), row-tiles 2*(w>>2)+{0,1} ----
    int nt = w & 3;
    int n15 = lane & 15;
    int quad = lane >> 4;

    bf16x8 bfrag[4];
    #pragma unroll
    for (int kk = 0; kk < 4; ++kk) {
        const unsigned short* W = (kk < 2) ? wl16 : wr16;
        int kbase = (kk & 1) * 32 + quad * 8;
        #pragma unroll
        for (int j = 0; j < 8; ++j)
            bfrag[kk][j] = (short)W[(kbase + j) * DFEAT + nt * 16 + n15];
    }
    float bias = bl[nt * 16 + n15];

    int tbase = (w >> 2) << 1;
    #pragma unroll
    for (int j = 0; j < 2; ++j) {
        int tt = tbase + j;
        int m = tt * 16 + n15;                       // local node row (A row)
        int grow = n0 + m; if (grow >= N) grow = N - 1;

        bf16x8 a0 = *(const bf16x8*)&means[m * MLD + quad * 8];
        bf16x8 a1 = *(const bf16x8*)&means[m * MLD + 32 + quad * 8];
        bf16x8 a2 = *(const bf16x8*)(xh + (size_t)grow * DFEAT + quad * 8);
        bf16x8 a3 = *(const bf16x8*)(xh + (size_t)grow * DFEAT + 32 + quad * 8);

        f32x4 c = {0.f, 0.f, 0.f, 0.f};
        c = __builtin_amdgcn_mfma_f32_16x16x32_bf16(a0, bfrag[0], c, 0, 0, 0);
        c = __builtin_amdgcn_mfma_f32_16x16x32_bf16(a1, bfrag[1], c, 0, 0, 0);
        c = __builtin_amdgcn_mfma_f32_16x16x32_bf16(a2, bfrag[2], c, 0, 0, 0);
        c = __builtin_amdgcn_mfma_f32_16x16x32_bf16(a3, bfrag[3], c, 0, 0, 0);

        #pragma unroll
        for (int r = 0; r < 4; ++r) {
            int orow = n0 + tt * 16 + quad * 4 + r;
            if (orow < N)
                out[(size_t)orow * DFEAT + nt * 16 + n15] = c[r] + bias;
        }
    }
}

extern "C" void kernel_launch(void* const* d_in, const int* in_sizes, int n_in,
                              void* d_out, int out_size, void* d_ws, size_t ws_size,
                              hipStream_t stream) {
    const float* x  = (const float*)d_in[0];
    const int*   ei = (const int*)d_in[1];     // [2,E] flat: src then dst
    const float* Wl = (const float*)d_in[2];
    const float* bl = (const float*)d_in[3];
    const float* Wr = (const float*)d_in[4];
    float* out = (float*)d_out;

    const int N = in_sizes[0] / DFEAT;         // 100000
    const int E = in_sizes[1] / 2;             // 1600000
    const int* src = ei;
    const int* dst = ei + E;

    const int nbuck = (N + 255) >> 8;          // 391 coarse buckets

    // ws: [bcnt 512][bfill 512][bbase 528][binned E][wl16 4096][wr16 4096][xh N*64]
    int* ws = (int*)d_ws;
    int* bcnt  = ws;
    int* bfill = bcnt + MAXBUCK;
    int* bbase = bfill + MAXBUCK;
    unsigned int* binned = (unsigned int*)(bbase + MAXBUCK + 16);
    unsigned short* wl16 = (unsigned short*)(binned + E);
    unsigned short* wr16 = wl16 + DFEAT * DFEAT;
    unsigned short* xh   = wr16 + DFEAT * DFEAT;

    hipMemsetAsync(bcnt, 0, 2 * MAXBUCK * sizeof(int), stream);

    int nx4 = N * DFEAT / 4;
    int convBlocks = (2048 + nx4 + 255) / 256;
    prep<<<convBlocks + 512, 256, 0, stream>>>(
        x, Wl, Wr, dst, xh, wl16, wr16, bcnt, nx4, convBlocks, E, nbuck);

    bscan<<<1, MAXBUCK, 0, stream>>>(bcnt, bbase, nbuck);
    binpass<<<512, 512, 0, stream>>>(src, dst, bbase, bfill, binned, E, nbuck);

    // swizzled grid: 8 * ceil(nbuck/8) * 4 blocks
    int mg = (nbuck + 7) >> 3;
    sage_fused<<<mg * 32, 512, 0, stream>>>(
        xh, binned, bbase, wl16, wr16, bl, out, N, nbuck);
}